// Round 10
// baseline (509.727 us; speedup 1.0000x reference)
//
#include <hip/hip_runtime.h>
#include <stdint.h>

// Problem constants (fixed by setup_inputs)
constexpr int B   = 2;
constexpr int T   = 2048;
constexpr int D   = 2048;
constexpr int H   = 32;
constexpr int KVH = 8;
constexpr int HD  = 64;          // head dim
constexpr int R   = B * T;       // 4096 rows
constexpr int OKV = KVH * HD;    // 512

using bf16x8 = __attribute__((ext_vector_type(8))) __bf16;
using f32x4  = __attribute__((ext_vector_type(4))) float;
using i32x4  = __attribute__((ext_vector_type(4))) int;

__device__ inline float fast_exp2(float x) {
#if __has_builtin(__builtin_amdgcn_exp2f)
    return __builtin_amdgcn_exp2f(x);    // v_exp_f32: computes 2^x
#else
    return exp2f(x);
#endif
}

__device__ inline uint16_t f2bf(float f) {
    uint32_t u = __float_as_uint(f);
    u += 0x7fff + ((u >> 16) & 1);   // RNE
    return (uint16_t)(u >> 16);
}

__device__ inline uint32_t pack_bf16(float a, float b) {
#if __has_builtin(__builtin_amdgcn_cvt_pk_bf16_f32)
    union { __attribute__((ext_vector_type(2))) __bf16 v; uint32_t u; } r;
    r.v = __builtin_amdgcn_cvt_pk_bf16_f32(a, b);
    return r.u;
#else
    return (uint32_t)f2bf(a) | ((uint32_t)f2bf(b) << 16);
#endif
}

// async global->LDS, 16B per lane; LDS dest = (wave-uniform) base + lane*16
__device__ inline void async16(const void* g, void* l) {
    __builtin_amdgcn_global_load_lds((const __attribute__((address_space(1))) unsigned int*)g,
                                     (__attribute__((address_space(3))) unsigned int*)l,
                                     16, 0, 0);
}

// ---------------- weight scales: mean(|w|), all 4 weights in one launch --------
__global__ void absmean4_kernel(const float* __restrict__ w0, const float* __restrict__ w1,
                                const float* __restrict__ w2, const float* __restrict__ w3,
                                double* __restrict__ sums) {
    __shared__ float red[256];
    const float* ws[4] = {w0, w1, w2, w3};
    const int ns[4] = {D * D, OKV * D, OKV * D, D * D};
    int wi = blockIdx.y;
    const float* w = ws[wi];
    int n = ns[wi];
    int tid = threadIdx.x;
    float s = 0.f;
    for (int i = blockIdx.x * 256 + tid; i < n; i += gridDim.x * 256)
        s += fabsf(w[i]);
    red[tid] = s;
    __syncthreads();
    for (int st = 128; st > 0; st >>= 1) {
        if (tid < st) red[tid] += red[tid + st];
        __syncthreads();
    }
    if (tid == 0) atomicAdd(&sums[wi], (double)red[0]);
}

// ---------------- ternary weight quantization, all 4 in one launch ----------------
__global__ void quantw4_kernel(const float* __restrict__ w0, const float* __restrict__ w1,
                               const float* __restrict__ w2, const float* __restrict__ w3,
                               int8_t* __restrict__ o0, int8_t* __restrict__ o1,
                               int8_t* __restrict__ o2, int8_t* __restrict__ o3,
                               const double* __restrict__ sums) {
    const float* ws[4] = {w0, w1, w2, w3};
    int8_t* os[4] = {o0, o1, o2, o3};
    const int ns[4] = {D * D, OKV * D, OKV * D, D * D};
    int wi = blockIdx.y;
    const float* w = ws[wi];
    int8_t* o = os[wi];
    int n = ns[wi];
    float wsc = fmaxf((float)(sums[wi] / (double)n), 1e-5f);
    for (int i = blockIdx.x * 256 + threadIdx.x; i < n; i += gridDim.x * 256) {
        float q = rintf(w[i] / wsc);
        q = fminf(fmaxf(q, -1.f), 1.f);
        o[i] = (int8_t)q;
    }
}

// ---------------- fused rmsnorm + absmax int8 quant for q,k,v ----------------
__global__ __launch_bounds__(256) void rmsq3_kernel(const float* __restrict__ X,
        const float* __restrict__ g0, const float* __restrict__ g1, const float* __restrict__ g2,
        int8_t* __restrict__ o0, int8_t* __restrict__ o1, int8_t* __restrict__ o2,
        float* __restrict__ s0, float* __restrict__ s1, float* __restrict__ s2) {
    __shared__ float red[256];
    int row = blockIdx.x, tid = threadIdx.x;
    const float* xr = X + (size_t)row * D;
    float xv[8];
    float ss = 0.f;
#pragma unroll
    for (int i = 0; i < 8; i++) { xv[i] = xr[tid + 256 * i]; ss += xv[i] * xv[i]; }
    red[tid] = ss;
    __syncthreads();
    for (int st = 128; st > 0; st >>= 1) {
        if (tid < st) red[tid] += red[tid + st];
        __syncthreads();
    }
    float rstd = 1.0f / sqrtf(red[0] / (float)D + 1e-6f);

    const float* gs[3] = {g0, g1, g2};
    int8_t* os[3] = {o0, o1, o2};
    float* sc[3] = {s0, s1, s2};
#pragma unroll
    for (int v = 0; v < 3; v++) {
        float xn[8];
        float amax = 0.f;
#pragma unroll
        for (int i = 0; i < 8; i++) {
            xn[i] = xv[i] * rstd * gs[v][tid + 256 * i];
            amax = fmaxf(amax, fabsf(xn[i]));
        }
        __syncthreads();
        red[tid] = amax;
        __syncthreads();
        for (int st = 128; st > 0; st >>= 1) {
            if (tid < st) red[tid] = fmaxf(red[tid], red[tid + st]);
            __syncthreads();
        }
        float xsv = fmaxf(red[0], 1e-5f);
        float q127 = 127.0f / xsv;
#pragma unroll
        for (int i = 0; i < 8; i++) {
            float q = rintf(xn[i] * q127);
            q = fminf(fmaxf(q, -128.f), 127.f);
            os[v][(size_t)row * D + tid + 256 * i] = (int8_t)q;
        }
        if (tid == 0) sc[v][row] = xsv;
    }
}

// ---------------- rmsnorm + quant (single, for o-proj input) ----------------
__global__ void rmsq_kernel(const float* __restrict__ X, const float* __restrict__ g,
                            int8_t* __restrict__ Xq, float* __restrict__ xs_out) {
    __shared__ float red[256];
    int row = blockIdx.x;
    int tid = threadIdx.x;
    const float* xr = X + (size_t)row * D;

    float ss = 0.f;
    for (int i = tid; i < D; i += 256) { float v = xr[i]; ss += v * v; }
    red[tid] = ss;
    __syncthreads();
    for (int st = 128; st > 0; st >>= 1) {
        if (tid < st) red[tid] += red[tid + st];
        __syncthreads();
    }
    float ms = red[0] / (float)D;
    float rstd = 1.0f / sqrtf(ms + 1e-6f);
    __syncthreads();

    float amax = 0.f;
    for (int i = tid; i < D; i += 256) {
        float xn = xr[i] * rstd * g[i];
        amax = fmaxf(amax, fabsf(xn));
    }
    red[tid] = amax;
    __syncthreads();
    for (int st = 128; st > 0; st >>= 1) {
        if (tid < st) red[tid] = fmaxf(red[tid], red[tid + st]);
        __syncthreads();
    }
    float xs = fmaxf(red[0], 1e-5f);

    for (int i = tid; i < D; i += 256) {
        float xn = xr[i] * rstd * g[i];
        float q = rintf(xn * 127.0f / xs);
        q = fminf(fmaxf(q, -128.f), 127.f);
        Xq[(size_t)row * D + i] = (int8_t)q;
    }
    if (tid == 0) xs_out[row] = xs;
}

// ---------------- i8 MFMA GEMM, wave = 32 rows x BN cols ----------------
// MODE 0: f32 output. MODE 1: bf16 output with fused RoPE (rope partners
// col and col+32 are acc[mt][nt] / acc[mt][nt+2] in the same lane).
template<int BN, int MODE>
__global__ __launch_bounds__(256) void gemm_i8_mfma(const int8_t* __restrict__ Xq,
                                                    const int8_t* __restrict__ W8,
                                                    void* __restrict__ outp,
                                                    const float* __restrict__ xs,
                                                    const double* __restrict__ wsum, int wi,
                                                    int nw, int O,
                                                    const float* __restrict__ cs,
                                                    const float* __restrict__ sn) {
    constexpr int NT = BN / 16;          // n-tiles per wave (full BN span)
    __shared__ __align__(16) uint8_t As[128 * 128];
    __shared__ __align__(16) uint8_t Bs[BN * 128];

    const int tid  = threadIdx.x;
    const int lane = tid & 63;
    const int wv   = tid >> 6;
    const int n    = lane & 15, quad = lane >> 4;
    const int row0 = blockIdx.y * 128;
    const int col0 = blockIdx.x * BN;

    i32x4 acc[2][NT] = {};

    for (int k0 = 0; k0 < D; k0 += 128) {
        __syncthreads();
#pragma unroll
        for (int j = 0; j < 4; j++) {
            int p = wv * 256 + j * 64 + lane;
            int r = p >> 3, s = p & 7;
            int c = s ^ (r & 7);
            async16(Xq + (size_t)(row0 + r) * D + k0 + c * 16,
                    &As[(size_t)(wv * 256 + j * 64) * 16]);
        }
#pragma unroll
        for (int j = 0; j < BN / 32; j++) {
            int p = wv * (BN * 2) + j * 64 + lane;
            int r = p >> 3, s = p & 7;
            int c = s ^ (r & 7);
            async16(W8 + (size_t)(col0 + r) * D + k0 + c * 16,
                    &Bs[(size_t)(wv * (BN * 2) + j * 64) * 16]);
        }
        __syncthreads();
#pragma unroll
        for (int t = 0; t < 2; t++) {
            i32x4 af[2], bfr[NT];
#pragma unroll
            for (int mt = 0; mt < 2; mt++) {
                int r = wv * 32 + mt * 16 + n;
                af[mt] = *(const i32x4*)&As[r * 128 + (((t * 4 + quad) ^ (r & 7)) * 16)];
            }
#pragma unroll
            for (int nt = 0; nt < NT; nt++) {
                int r = nt * 16 + n;
                bfr[nt] = *(const i32x4*)&Bs[r * 128 + (((t * 4 + quad) ^ (r & 7)) * 16)];
            }
#pragma unroll
            for (int mt = 0; mt < 2; mt++)
#pragma unroll
                for (int nt = 0; nt < NT; nt++)
                    acc[mt][nt] = __builtin_amdgcn_mfma_i32_16x16x64_i8(af[mt], bfr[nt], acc[mt][nt], 0, 0, 0);
        }
    }
    float w = fmaxf((float)(wsum[wi] / (double)nw), 1e-5f);
#pragma unroll
    for (int mt = 0; mt < 2; mt++) {
#pragma unroll
        for (int r2 = 0; r2 < 4; r2++) {
            int row = row0 + wv * 32 + mt * 16 + quad * 4 + r2;
            float f = w * xs[row] * (1.0f / 127.0f);
            if (MODE == 0) {
                float* out = (float*)outp;
#pragma unroll
                for (int nt = 0; nt < NT; nt++)
                    out[(size_t)row * O + col0 + nt * 16 + n] = (float)acc[mt][nt][r2] * f;
            } else {
                uint16_t* out = (uint16_t*)outp;
                int t = row & (T - 1);
#pragma unroll
                for (int nt = 0; nt < NT; nt++) {
                    if ((nt & 3) >= 2) continue;   // rope pair handled at nt, nt+2
                    int i = (nt * 16 + n) & 63;
                    float a  = (float)acc[mt][nt][r2] * f;
                    float bb = (float)acc[mt][nt + 2][r2] * f;
                    float c0 = cs[t * HD + i],      s0 = sn[t * HD + i];
                    float c1 = cs[t * HD + i + 32], s1 = sn[t * HD + i + 32];
                    out[(size_t)row * O + col0 + nt * 16 + n]       = f2bf(a * c0 - bb * s0);
                    out[(size_t)row * O + col0 + (nt + 2) * 16 + n] = f2bf(bb * c1 + a * s1);
                }
            }
        }
    }
}

// ---------------- V transpose: [t][kvh*64+d] f32 -> [b*KVH+kvh][d][t] bf16 --------
__global__ __launch_bounds__(256) void vtrans_kernel(const float* __restrict__ vb,
                                                     uint16_t* __restrict__ vt) {
    __shared__ float tile[64][65];
    int t0 = blockIdx.x * 64;
    int hb = blockIdx.y;              // b*KVH + kvh
    int b = hb >> 3, kvh = hb & 7;
    int tid = threadIdx.x;
    int r = tid >> 2, cg = (tid & 3) * 16;
#pragma unroll
    for (int j = 0; j < 4; j++) {
        float4 v4 = *(const float4*)(vb + (size_t)(b * T + t0 + r) * OKV + kvh * HD + cg + j * 4);
        tile[r][cg + j * 4 + 0] = v4.x;
        tile[r][cg + j * 4 + 1] = v4.y;
        tile[r][cg + j * 4 + 2] = v4.z;
        tile[r][cg + j * 4 + 3] = v4.w;
    }
    __syncthreads();
    int d = tid >> 2, tg = (tid & 3) * 16;
    uint16_t pk[16];
#pragma unroll
    for (int j = 0; j < 16; j++) pk[j] = f2bf(tile[tg + j][d]);
    *(uint4*)(vt + ((size_t)hb * 64 + d) * T + t0 + tg)     = *(uint4*)&pk[0];
    *(uint4*)(vt + ((size_t)hb * 64 + d) * T + t0 + tg + 8) = *(uint4*)&pk[8];
}

// ---------------- MFMA flash attention: 16x16 frags, 3 blocks/CU ----------
// grid (16, H, B) reversed (big strips first). Block covers one 128-q strip;
// wave wv owns 2 q-tiles: strip*128 + wv*32 + {0,16}. K [key][d] and V^T
// [d][key] double-buffered via swizzled global_load_lds with early prefetch.
// l accumulated via ones-row MFMA.
__global__ __launch_bounds__(256, 3) void attn_mfma_kernel(const uint16_t* __restrict__ qh,
                                                           const uint16_t* __restrict__ kh,
                                                           const uint16_t* __restrict__ vt,
                                                           float* __restrict__ out) {
    __shared__ __align__(16) uint16_t KsB[2][64 * 64];
    __shared__ __align__(16) uint16_t VtB[2][64 * 64];
    __shared__ __align__(16) uint16_t Pw[4][16 * 72];   // per-wave P [q][key] (one tile)

    const int tid  = threadIdx.x;
    const int lane = tid & 63;
    const int wv   = tid >> 6;
    const int pr = 15 - (int)blockIdx.x;   // big strips dispatch first
    const int h = blockIdx.y, b = blockIdx.z;
    const int kvh = h >> 2;                // n_rep = 4
    const int n = lane & 15, quad = lane >> 4;
    const float SC = 0.125f * 1.44269504089f;   // score -> log2 units

    // ones A-frag for l-accumulation MFMA
    union { bf16x8 v; uint16_t u[8]; } onesf;
#pragma unroll
    for (int j = 0; j < 8; j++) onesf.u[j] = 0x3F80;   // bf16 1.0

    int q_lo[2];
#pragma unroll
    for (int i = 0; i < 2; i++) q_lo[i] = pr * 128 + wv * 32 + i * 16;

    bf16x8 qf[2][2];
#pragma unroll
    for (int i = 0; i < 2; i++) {
        const uint16_t* qp = qh + (size_t)(b * T + q_lo[i] + n) * D + h * HD + quad * 8;
        qf[i][0] = *(const bf16x8*)(qp);
        qf[i][1] = *(const bf16x8*)(qp + 32);
    }

    f32x4 o[2][4] = {};
    f32x4 lacc[2] = {};
    float m[2];
#pragma unroll
    for (int i = 0; i < 2; i++) m[i] = -INFINITY;

    const uint16_t* kbase = kh + (size_t)b * T * OKV + kvh * HD;
    const uint16_t* vbase = vt + (size_t)(b * KVH + kvh) * 64 * T;

    const int nch = 2 * pr + 2;

    // stage chunk 0 -> buf 0
#pragma unroll
    for (int j = 0; j < 2; j++) {
        int pp = wv * 128 + j * 64 + lane;
        int r = pp >> 3, sl = pp & 7;
        int c = sl ^ (r & 7);
        async16(kbase + (size_t)r * OKV + c * 8, &KsB[0][(wv * 128 + j * 64) * 8]);
        async16(vbase + (size_t)r * T + c * 8,   &VtB[0][(wv * 128 + j * 64) * 8]);
    }
    __syncthreads();

    for (int ch = 0; ch < nch; ch++) {
        const int cur = ch & 1;
        if (ch + 1 < nch) {   // prefetch next chunk into alternate buffer
            const int t1 = (ch + 1) * 64;
#pragma unroll
            for (int j = 0; j < 2; j++) {
                int pp = wv * 128 + j * 64 + lane;
                int r = pp >> 3, sl = pp & 7;
                int c = sl ^ (r & 7);
                async16(kbase + (size_t)(t1 + r) * OKV + c * 8, &KsB[cur ^ 1][(wv * 128 + j * 64) * 8]);
                async16(vbase + (size_t)r * T + t1 + c * 8,     &VtB[cur ^ 1][(wv * 128 + j * 64) * 8]);
            }
        }
        const int t0 = ch * 64;

        // K / V^T fragments from current buffer
        bf16x8 kf[2][4], vf[2][4];
#pragma unroll
        for (int ks = 0; ks < 2; ks++)
#pragma unroll
            for (int mt = 0; mt < 4; mt++) {
                int r = mt * 16 + n;
                int cc = (((ks * 4 + quad) ^ (n & 7)) * 8);
                kf[ks][mt] = *(const bf16x8*)&KsB[cur][r * 64 + cc];
                vf[ks][mt] = *(const bf16x8*)&VtB[cur][r * 64 + cc];
            }

        // fused per-tile: QK^T -> softmax -> P roundtrip -> PV^T (+ l via ones-MFMA)
#pragma unroll
        for (int i = 0; i < 2; i++) {
            if (t0 > q_lo[i] + 15) continue;
            f32x4 sv[4] = {};
#pragma unroll
            for (int ks = 0; ks < 2; ks++)
#pragma unroll
                for (int mt = 0; mt < 4; mt++)
                    sv[mt] = __builtin_amdgcn_mfma_f32_16x16x32_bf16(kf[ks][mt], qf[i][ks], sv[mt], 0, 0, 0);

            const int qg = q_lo[i] + n;
            const bool diag = (t0 + 63 > q_lo[i]);
            float mloc = -INFINITY;
#pragma unroll
            for (int mt = 0; mt < 4; mt++)
#pragma unroll
                for (int r2 = 0; r2 < 4; r2++) {
                    float x = sv[mt][r2];
                    if (diag) {
                        int kg = t0 + mt * 16 + quad * 4 + r2;
                        x = (kg > qg) ? -INFINITY : x;
                        sv[mt][r2] = x;
                    }
                    mloc = fmaxf(mloc, x);
                }
            mloc = fmaxf(mloc, __shfl_xor(mloc, 16));
            mloc = fmaxf(mloc, __shfl_xor(mloc, 32));
            bool upd = (mloc > m[i]);
            if (__ballot(upd)) {
                float mnew = fmaxf(m[i], mloc);
                float corr = upd ? fast_exp2((m[i] - mnew) * SC) : 1.0f;  // first chunk: 2^-inf=0
                m[i] = mnew;
#pragma unroll
                for (int mt = 0; mt < 4; mt++)
#pragma unroll
                    for (int r2 = 0; r2 < 4; r2++) o[i][mt][r2] *= corr;
                lacc[i][0] *= corr;
            }
            float msc = m[i] * SC;
#pragma unroll
            for (int mt = 0; mt < 4; mt++) {
                float pv[4];
#pragma unroll
                for (int r2 = 0; r2 < 4; r2++)
                    pv[r2] = fast_exp2(__builtin_fmaf(sv[mt][r2], SC, -msc));
                uint2 w2;
                w2.x = pack_bf16(pv[0], pv[1]);
                w2.y = pack_bf16(pv[2], pv[3]);
                *(uint2*)&Pw[wv][n * 72 + mt * 16 + quad * 4] = w2;
            }
#pragma unroll
            for (int ks = 0; ks < 2; ks++) {
                bf16x8 pf = *(const bf16x8*)&Pw[wv][n * 72 + ks * 32 + quad * 8];
#pragma unroll
                for (int mt = 0; mt < 4; mt++)
                    o[i][mt] = __builtin_amdgcn_mfma_f32_16x16x32_bf16(vf[ks][mt], pf, o[i][mt], 0, 0, 0);
                lacc[i] = __builtin_amdgcn_mfma_f32_16x16x32_bf16(onesf.v, pf, lacc[i], 0, 0, 0);
            }
        }
        __syncthreads();   // publish next buffer (prefetch had full compute to land)
    }

#pragma unroll
    for (int i = 0; i < 2; i++) {
        int qg = q_lo[i] + n;
        float inv = 1.0f / lacc[i][0];
#pragma unroll
        for (int mt = 0; mt < 4; mt++) {
            f32x4 ov;
#pragma unroll
            for (int r2 = 0; r2 < 4; r2++) ov[r2] = o[i][mt][r2] * inv;
            *(f32x4*)(out + (size_t)(b * T + qg) * D + h * HD + mt * 16 + quad * 4) = ov;
        }
    }
}

// ---------------- launch ----------------
extern "C" void kernel_launch(void* const* d_in, const int* in_sizes, int n_in,
                              void* d_out, int out_size, void* d_ws, size_t ws_size,
                              hipStream_t stream) {
    const float* x   = (const float*)d_in[0];
    const float* cs  = (const float*)d_in[1];
    const float* sn  = (const float*)d_in[2];
    const float* wq  = (const float*)d_in[3];
    const float* wk  = (const float*)d_in[4];
    const float* wv  = (const float*)d_in[5];
    const float* wo  = (const float*)d_in[6];
    const float* gq  = (const float*)d_in[7];
    const float* gk  = (const float*)d_in[8];
    const float* gv  = (const float*)d_in[9];
    const float* go  = (const float*)d_in[10];
    float* out = (float*)d_out;

    uint8_t* w = (uint8_t*)d_ws;
    double* wsum  = (double*)w;
    float* xs     = (float*)(w + 256);
    size_t off = 256 + 4 * (size_t)R * 4;
    int8_t* Wq8 = (int8_t*)(w + off); off += (size_t)D * D;
    int8_t* Wk8 = (int8_t*)(w + off); off += (size_t)OKV * D;
    int8_t* Wv8 = (int8_t*)(w + off); off += (size_t)OKV * D;
    int8_t* Wo8 = (int8_t*)(w + off); off += (size_t)D * D;
    int8_t* Xq_q = (int8_t*)(w + off); off += (size_t)R * D;
    int8_t* Xq_k = (int8_t*)(w + off); off += (size_t)R * D;
    int8_t* Xq_v = (int8_t*)(w + off); off += (size_t)R * D;
    float* ab = (float*)(w + off); off += (size_t)R * D * 4;      // attention output (f32)
    float* vb = (float*)(w + off); off += (size_t)R * OKV * 4;    // v proj (f32)
    uint16_t* qhb = (uint16_t*)(w + off); off += (size_t)R * D * 2;
    // overlays (regions dead by the time they're written):
    uint16_t* khb = (uint16_t*)Xq_v;   // written by k-gemm AFTER v-gemm consumed Xq_v
    uint16_t* vtb = (uint16_t*)Xq_k;   // written by vtrans AFTER k-gemm consumed Xq_k
    int8_t*   Aq8 = Xq_q;              // written by rmsq AFTER q-gemm consumed Xq_q

    (void)hipMemsetAsync(wsum, 0, 64, stream);

    absmean4_kernel<<<dim3(256, 4), 256, 0, stream>>>(wq, wk, wv, wo, wsum);
    quantw4_kernel<<<dim3(1024, 4), 256, 0, stream>>>(wq, wk, wv, wo, Wq8, Wk8, Wv8, Wo8, wsum);

    rmsq3_kernel<<<R, 256, 0, stream>>>(x, gq, gk, gv, Xq_q, Xq_k, Xq_v,
                                        xs + 0 * R, xs + 1 * R, xs + 2 * R);

    // q (rope fused, bf16 out), then v (f32), then k (rope fused, bf16 over Xq_v)
    gemm_i8_mfma<128, 1><<<dim3(D / 128, R / 128), 256, 0, stream>>>(
        Xq_q, Wq8, qhb, xs + 0 * R, wsum, 0, D * D, D, cs, sn);
    gemm_i8_mfma<64, 0><<<dim3(OKV / 64, R / 128), 256, 0, stream>>>(
        Xq_v, Wv8, vb, xs + 2 * R, wsum, 2, OKV * D, OKV, cs, sn);
    gemm_i8_mfma<64, 1><<<dim3(OKV / 64, R / 128), 256, 0, stream>>>(
        Xq_k, Wk8, khb, xs + 1 * R, wsum, 1, OKV * D, OKV, cs, sn);

    vtrans_kernel<<<dim3(T / 64, B * KVH), 256, 0, stream>>>(vb, vtb);

    attn_mfma_kernel<<<dim3(16, H, B), 256, 0, stream>>>(qhb, khb, vtb, ab);

    rmsq_kernel<<<R, 256, 0, stream>>>(ab, go, Aq8, xs + 3 * R);
    gemm_i8_mfma<128, 0><<<dim3(D / 128, R / 128), 256, 0, stream>>>(
        Aq8, Wo8, out, xs + 3 * R, wsum, 3, D * D, D, cs, sn);
}

// Round 11
// 382.446 us; speedup vs baseline: 1.3328x; 1.3328x over previous
//
#include <hip/hip_runtime.h>
#include <stdint.h>

// Problem constants (fixed by setup_inputs)
constexpr int B   = 2;
constexpr int T   = 2048;
constexpr int D   = 2048;
constexpr int H   = 32;
constexpr int KVH = 8;
constexpr int HD  = 64;          // head dim
constexpr int R   = B * T;       // 4096 rows
constexpr int OKV = KVH * HD;    // 512

using bf16x8 = __attribute__((ext_vector_type(8))) __bf16;
using f32x4  = __attribute__((ext_vector_type(4))) float;
using i32x4  = __attribute__((ext_vector_type(4))) int;

__device__ inline float fast_exp2(float x) {
#if __has_builtin(__builtin_amdgcn_exp2f)
    return __builtin_amdgcn_exp2f(x);    // v_exp_f32: computes 2^x
#else
    return exp2f(x);
#endif
}

__device__ inline uint16_t f2bf(float f) {
    uint32_t u = __float_as_uint(f);
    u += 0x7fff + ((u >> 16) & 1);   // RNE
    return (uint16_t)(u >> 16);
}

__device__ inline uint32_t pack_bf16(float a, float b) {
#if __has_builtin(__builtin_amdgcn_cvt_pk_bf16_f32)
    union { __attribute__((ext_vector_type(2))) __bf16 v; uint32_t u; } r;
    r.v = __builtin_amdgcn_cvt_pk_bf16_f32(a, b);
    return r.u;
#else
    return (uint32_t)f2bf(a) | ((uint32_t)f2bf(b) << 16);
#endif
}

// async global->LDS, 16B per lane; LDS dest = (wave-uniform) base + lane*16
__device__ inline void async16(const void* g, void* l) {
    __builtin_amdgcn_global_load_lds((const __attribute__((address_space(1))) unsigned int*)g,
                                     (__attribute__((address_space(3))) unsigned int*)l,
                                     16, 0, 0);
}

// ---------------- weight scales: mean(|w|), all 4 weights in one launch --------
__global__ void absmean4_kernel(const float* __restrict__ w0, const float* __restrict__ w1,
                                const float* __restrict__ w2, const float* __restrict__ w3,
                                double* __restrict__ sums) {
    __shared__ float red[256];
    const float* ws[4] = {w0, w1, w2, w3};
    const int ns[4] = {D * D, OKV * D, OKV * D, D * D};
    int wi = blockIdx.y;
    const float* w = ws[wi];
    int n = ns[wi];
    int tid = threadIdx.x;
    float s = 0.f;
    for (int i = blockIdx.x * 256 + tid; i < n; i += gridDim.x * 256)
        s += fabsf(w[i]);
    red[tid] = s;
    __syncthreads();
    for (int st = 128; st > 0; st >>= 1) {
        if (tid < st) red[tid] += red[tid + st];
        __syncthreads();
    }
    if (tid == 0) atomicAdd(&sums[wi], (double)red[0]);
}

// ---------------- ternary weight quantization, all 4 in one launch ----------------
__global__ void quantw4_kernel(const float* __restrict__ w0, const float* __restrict__ w1,
                               const float* __restrict__ w2, const float* __restrict__ w3,
                               int8_t* __restrict__ o0, int8_t* __restrict__ o1,
                               int8_t* __restrict__ o2, int8_t* __restrict__ o3,
                               const double* __restrict__ sums) {
    const float* ws[4] = {w0, w1, w2, w3};
    int8_t* os[4] = {o0, o1, o2, o3};
    const int ns[4] = {D * D, OKV * D, OKV * D, D * D};
    int wi = blockIdx.y;
    const float* w = ws[wi];
    int8_t* o = os[wi];
    int n = ns[wi];
    float wsc = fmaxf((float)(sums[wi] / (double)n), 1e-5f);
    for (int i = blockIdx.x * 256 + threadIdx.x; i < n; i += gridDim.x * 256) {
        float q = rintf(w[i] / wsc);
        q = fminf(fmaxf(q, -1.f), 1.f);
        o[i] = (int8_t)q;
    }
}

// ---------------- fused rmsnorm + absmax int8 quant for q,k,v ----------------
__global__ __launch_bounds__(256) void rmsq3_kernel(const float* __restrict__ X,
        const float* __restrict__ g0, const float* __restrict__ g1, const float* __restrict__ g2,
        int8_t* __restrict__ o0, int8_t* __restrict__ o1, int8_t* __restrict__ o2,
        float* __restrict__ s0, float* __restrict__ s1, float* __restrict__ s2) {
    __shared__ float red[256];
    int row = blockIdx.x, tid = threadIdx.x;
    const float* xr = X + (size_t)row * D;
    float xv[8];
    float ss = 0.f;
#pragma unroll
    for (int i = 0; i < 8; i++) { xv[i] = xr[tid + 256 * i]; ss += xv[i] * xv[i]; }
    red[tid] = ss;
    __syncthreads();
    for (int st = 128; st > 0; st >>= 1) {
        if (tid < st) red[tid] += red[tid + st];
        __syncthreads();
    }
    float rstd = 1.0f / sqrtf(red[0] / (float)D + 1e-6f);

    const float* gs[3] = {g0, g1, g2};
    int8_t* os[3] = {o0, o1, o2};
    float* sc[3] = {s0, s1, s2};
#pragma unroll
    for (int v = 0; v < 3; v++) {
        float xn[8];
        float amax = 0.f;
#pragma unroll
        for (int i = 0; i < 8; i++) {
            xn[i] = xv[i] * rstd * gs[v][tid + 256 * i];
            amax = fmaxf(amax, fabsf(xn[i]));
        }
        __syncthreads();
        red[tid] = amax;
        __syncthreads();
        for (int st = 128; st > 0; st >>= 1) {
            if (tid < st) red[tid] = fmaxf(red[tid], red[tid + st]);
            __syncthreads();
        }
        float xsv = fmaxf(red[0], 1e-5f);
        float q127 = 127.0f / xsv;
#pragma unroll
        for (int i = 0; i < 8; i++) {
            float q = rintf(xn[i] * q127);
            q = fminf(fmaxf(q, -128.f), 127.f);
            os[v][(size_t)row * D + tid + 256 * i] = (int8_t)q;
        }
        if (tid == 0) sc[v][row] = xsv;
    }
}

// ---------------- rmsnorm + quant (single, for o-proj input) ----------------
__global__ void rmsq_kernel(const float* __restrict__ X, const float* __restrict__ g,
                            int8_t* __restrict__ Xq, float* __restrict__ xs_out) {
    __shared__ float red[256];
    int row = blockIdx.x;
    int tid = threadIdx.x;
    const float* xr = X + (size_t)row * D;

    float ss = 0.f;
    for (int i = tid; i < D; i += 256) { float v = xr[i]; ss += v * v; }
    red[tid] = ss;
    __syncthreads();
    for (int st = 128; st > 0; st >>= 1) {
        if (tid < st) red[tid] += red[tid + st];
        __syncthreads();
    }
    float ms = red[0] / (float)D;
    float rstd = 1.0f / sqrtf(ms + 1e-6f);
    __syncthreads();

    float amax = 0.f;
    for (int i = tid; i < D; i += 256) {
        float xn = xr[i] * rstd * g[i];
        amax = fmaxf(amax, fabsf(xn));
    }
    red[tid] = amax;
    __syncthreads();
    for (int st = 128; st > 0; st >>= 1) {
        if (tid < st) red[tid] = fmaxf(red[tid], red[tid + st]);
        __syncthreads();
    }
    float xs = fmaxf(red[0], 1e-5f);

    for (int i = tid; i < D; i += 256) {
        float xn = xr[i] * rstd * g[i];
        float q = rintf(xn * 127.0f / xs);
        q = fminf(fmaxf(q, -128.f), 127.f);
        Xq[(size_t)row * D + i] = (int8_t)q;
    }
    if (tid == 0) xs_out[row] = xs;
}

// ---------------- i8 MFMA GEMM, wave = 32 rows x BN cols ----------------
// MODE 0: f32 output. MODE 1: bf16 output with fused RoPE (rope partners
// col and col+32 are acc[mt][nt] / acc[mt][nt+2] in the same lane).
template<int BN, int MODE>
__global__ __launch_bounds__(256) void gemm_i8_mfma(const int8_t* __restrict__ Xq,
                                                    const int8_t* __restrict__ W8,
                                                    void* __restrict__ outp,
                                                    const float* __restrict__ xs,
                                                    const double* __restrict__ wsum, int wi,
                                                    int nw, int O,
                                                    const float* __restrict__ cs,
                                                    const float* __restrict__ sn) {
    constexpr int NT = BN / 16;          // n-tiles per wave (full BN span)
    __shared__ __align__(16) uint8_t As[128 * 128];
    __shared__ __align__(16) uint8_t Bs[BN * 128];

    const int tid  = threadIdx.x;
    const int lane = tid & 63;
    const int wv   = tid >> 6;
    const int n    = lane & 15, quad = lane >> 4;
    const int row0 = blockIdx.y * 128;
    const int col0 = blockIdx.x * BN;

    i32x4 acc[2][NT] = {};

    for (int k0 = 0; k0 < D; k0 += 128) {
        __syncthreads();
#pragma unroll
        for (int j = 0; j < 4; j++) {
            int p = wv * 256 + j * 64 + lane;
            int r = p >> 3, s = p & 7;
            int c = s ^ (r & 7);
            async16(Xq + (size_t)(row0 + r) * D + k0 + c * 16,
                    &As[(size_t)(wv * 256 + j * 64) * 16]);
        }
#pragma unroll
        for (int j = 0; j < BN / 32; j++) {
            int p = wv * (BN * 2) + j * 64 + lane;
            int r = p >> 3, s = p & 7;
            int c = s ^ (r & 7);
            async16(W8 + (size_t)(col0 + r) * D + k0 + c * 16,
                    &Bs[(size_t)(wv * (BN * 2) + j * 64) * 16]);
        }
        __syncthreads();
#pragma unroll
        for (int t = 0; t < 2; t++) {
            i32x4 af[2], bfr[NT];
#pragma unroll
            for (int mt = 0; mt < 2; mt++) {
                int r = wv * 32 + mt * 16 + n;
                af[mt] = *(const i32x4*)&As[r * 128 + (((t * 4 + quad) ^ (r & 7)) * 16)];
            }
#pragma unroll
            for (int nt = 0; nt < NT; nt++) {
                int r = nt * 16 + n;
                bfr[nt] = *(const i32x4*)&Bs[r * 128 + (((t * 4 + quad) ^ (r & 7)) * 16)];
            }
#pragma unroll
            for (int mt = 0; mt < 2; mt++)
#pragma unroll
                for (int nt = 0; nt < NT; nt++)
                    acc[mt][nt] = __builtin_amdgcn_mfma_i32_16x16x64_i8(af[mt], bfr[nt], acc[mt][nt], 0, 0, 0);
        }
    }
    float w = fmaxf((float)(wsum[wi] / (double)nw), 1e-5f);
#pragma unroll
    for (int mt = 0; mt < 2; mt++) {
#pragma unroll
        for (int r2 = 0; r2 < 4; r2++) {
            int row = row0 + wv * 32 + mt * 16 + quad * 4 + r2;
            float f = w * xs[row] * (1.0f / 127.0f);
            if (MODE == 0) {
                float* out = (float*)outp;
#pragma unroll
                for (int nt = 0; nt < NT; nt++)
                    out[(size_t)row * O + col0 + nt * 16 + n] = (float)acc[mt][nt][r2] * f;
            } else {
                uint16_t* out = (uint16_t*)outp;
                int t = row & (T - 1);
#pragma unroll
                for (int nt = 0; nt < NT; nt++) {
                    if ((nt & 3) >= 2) continue;   // rope pair handled at nt, nt+2
                    int i = (nt * 16 + n) & 63;
                    float a  = (float)acc[mt][nt][r2] * f;
                    float bb = (float)acc[mt][nt + 2][r2] * f;
                    float c0 = cs[t * HD + i],      s0 = sn[t * HD + i];
                    float c1 = cs[t * HD + i + 32], s1 = sn[t * HD + i + 32];
                    out[(size_t)row * O + col0 + nt * 16 + n]       = f2bf(a * c0 - bb * s0);
                    out[(size_t)row * O + col0 + (nt + 2) * 16 + n] = f2bf(bb * c1 + a * s1);
                }
            }
        }
    }
}

// ---------------- V transpose: [t][kvh*64+d] f32 -> [b*KVH+kvh][d][t] bf16 --------
__global__ __launch_bounds__(256) void vtrans_kernel(const float* __restrict__ vb,
                                                     uint16_t* __restrict__ vt) {
    __shared__ float tile[64][65];
    int t0 = blockIdx.x * 64;
    int hb = blockIdx.y;              // b*KVH + kvh
    int b = hb >> 3, kvh = hb & 7;
    int tid = threadIdx.x;
    int r = tid >> 2, cg = (tid & 3) * 16;
#pragma unroll
    for (int j = 0; j < 4; j++) {
        float4 v4 = *(const float4*)(vb + (size_t)(b * T + t0 + r) * OKV + kvh * HD + cg + j * 4);
        tile[r][cg + j * 4 + 0] = v4.x;
        tile[r][cg + j * 4 + 1] = v4.y;
        tile[r][cg + j * 4 + 2] = v4.z;
        tile[r][cg + j * 4 + 3] = v4.w;
    }
    __syncthreads();
    int d = tid >> 2, tg = (tid & 3) * 16;
    uint16_t pk[16];
#pragma unroll
    for (int j = 0; j < 16; j++) pk[j] = f2bf(tile[tg + j][d]);
    *(uint4*)(vt + ((size_t)hb * 64 + d) * T + t0 + tg)     = *(uint4*)&pk[0];
    *(uint4*)(vt + ((size_t)hb * 64 + d) * T + t0 + tg + 8) = *(uint4*)&pk[8];
}

// ---------------- MFMA flash attention: 2 blocks/CU, dbuf staging (r8 design) ----
// grid (8, H, B) = 512 blocks (2/CU, 2 waves/SIMD). Block p handles causal
// strips p and 15-p (128 q each); wave wv owns 4 q-tiles:
// strip*128 + wv*32 + {0,16}. l accumulated via ones-row MFMA (no shfl tree).
__global__ __launch_bounds__(256, 2) void attn_mfma_kernel(const uint16_t* __restrict__ qh,
                                                           const uint16_t* __restrict__ kh,
                                                           const uint16_t* __restrict__ vt,
                                                           float* __restrict__ out) {
    __shared__ __align__(16) uint16_t KsB[2][64 * 64];
    __shared__ __align__(16) uint16_t VtB[2][64 * 64];
    __shared__ __align__(16) uint16_t Pw[4][16 * 72];   // per-wave P [q][key] (one tile)

    const int tid  = threadIdx.x;
    const int lane = tid & 63;
    const int wv   = tid >> 6;
    const int p = blockIdx.x, h = blockIdx.y, b = blockIdx.z;
    const int kvh = h >> 2;               // n_rep = 4
    const int n = lane & 15, quad = lane >> 4;
    const float SC = 0.125f * 1.44269504089f;   // score -> log2 units

    // ones A-frag for l-accumulation MFMA
    union { bf16x8 v; uint16_t u[8]; } onesf;
#pragma unroll
    for (int j = 0; j < 8; j++) onesf.u[j] = 0x3F80;   // bf16 1.0

    // 4 q-tiles: 0..1 strip p, 2..3 strip 15-p
    int q_lo[4];
#pragma unroll
    for (int i = 0; i < 4; i++)
        q_lo[i] = ((i < 2) ? p : (15 - p)) * 128 + wv * 32 + (i & 1) * 16;

    bf16x8 qf[4][2];
#pragma unroll
    for (int i = 0; i < 4; i++) {
        const uint16_t* qp = qh + (size_t)(b * T + q_lo[i] + n) * D + h * HD + quad * 8;
        qf[i][0] = *(const bf16x8*)(qp);
        qf[i][1] = *(const bf16x8*)(qp + 32);
    }

    f32x4 o[4][4] = {};
    f32x4 lacc[4] = {};
    float m[4];
#pragma unroll
    for (int i = 0; i < 4; i++) m[i] = -INFINITY;

    const uint16_t* kbase = kh + (size_t)b * T * OKV + kvh * HD;
    const uint16_t* vbase = vt + (size_t)(b * KVH + kvh) * 64 * T;

    const int nch = 32 - 2 * p;           // chunks for the longer strip (15-p)

    // stage chunk 0 -> buf 0
#pragma unroll
    for (int j = 0; j < 2; j++) {
        int pp = wv * 128 + j * 64 + lane;
        int r = pp >> 3, sl = pp & 7;
        int c = sl ^ (r & 7);
        async16(kbase + (size_t)r * OKV + c * 8, &KsB[0][(wv * 128 + j * 64) * 8]);
        async16(vbase + (size_t)r * T + c * 8,   &VtB[0][(wv * 128 + j * 64) * 8]);
    }
    __syncthreads();

    for (int ch = 0; ch < nch; ch++) {
        const int cur = ch & 1;
        if (ch + 1 < nch) {   // prefetch next chunk into alternate buffer
            const int t1 = (ch + 1) * 64;
#pragma unroll
            for (int j = 0; j < 2; j++) {
                int pp = wv * 128 + j * 64 + lane;
                int r = pp >> 3, sl = pp & 7;
                int c = sl ^ (r & 7);
                async16(kbase + (size_t)(t1 + r) * OKV + c * 8, &KsB[cur ^ 1][(wv * 128 + j * 64) * 8]);
                async16(vbase + (size_t)r * T + t1 + c * 8,     &VtB[cur ^ 1][(wv * 128 + j * 64) * 8]);
            }
        }
        const int t0 = ch * 64;

        // K / V^T fragments from current buffer
        bf16x8 kf[2][4], vf[2][4];
#pragma unroll
        for (int ks = 0; ks < 2; ks++)
#pragma unroll
            for (int mt = 0; mt < 4; mt++) {
                int r = mt * 16 + n;
                int cc = (((ks * 4 + quad) ^ (n & 7)) * 8);
                kf[ks][mt] = *(const bf16x8*)&KsB[cur][r * 64 + cc];
                vf[ks][mt] = *(const bf16x8*)&VtB[cur][r * 64 + cc];
            }

        // fused per-tile: QK^T -> softmax -> P roundtrip -> PV^T (+ l via ones-MFMA)
#pragma unroll
        for (int i = 0; i < 4; i++) {
            if (t0 > q_lo[i] + 15) continue;
            f32x4 sv[4] = {};
#pragma unroll
            for (int ks = 0; ks < 2; ks++)
#pragma unroll
                for (int mt = 0; mt < 4; mt++)
                    sv[mt] = __builtin_amdgcn_mfma_f32_16x16x32_bf16(kf[ks][mt], qf[i][ks], sv[mt], 0, 0, 0);

            const int qg = q_lo[i] + n;
            const bool diag = (t0 + 63 > q_lo[i]);
            float mloc = -INFINITY;
#pragma unroll
            for (int mt = 0; mt < 4; mt++)
#pragma unroll
                for (int r2 = 0; r2 < 4; r2++) {
                    float x = sv[mt][r2];
                    if (diag) {
                        int kg = t0 + mt * 16 + quad * 4 + r2;
                        x = (kg > qg) ? -INFINITY : x;
                        sv[mt][r2] = x;
                    }
                    mloc = fmaxf(mloc, x);
                }
            mloc = fmaxf(mloc, __shfl_xor(mloc, 16));
            mloc = fmaxf(mloc, __shfl_xor(mloc, 32));
            bool upd = (mloc > m[i]);
            if (__ballot(upd)) {
                float mnew = fmaxf(m[i], mloc);
                float corr = upd ? fast_exp2((m[i] - mnew) * SC) : 1.0f;  // first chunk: 2^-inf=0
                m[i] = mnew;
#pragma unroll
                for (int mt = 0; mt < 4; mt++)
#pragma unroll
                    for (int r2 = 0; r2 < 4; r2++) o[i][mt][r2] *= corr;
                lacc[i][0] *= corr;
            }
            float msc = m[i] * SC;
#pragma unroll
            for (int mt = 0; mt < 4; mt++) {
                float pv[4];
#pragma unroll
                for (int r2 = 0; r2 < 4; r2++)
                    pv[r2] = fast_exp2(__builtin_fmaf(sv[mt][r2], SC, -msc));
                uint2 w2;
                w2.x = pack_bf16(pv[0], pv[1]);
                w2.y = pack_bf16(pv[2], pv[3]);
                *(uint2*)&Pw[wv][n * 72 + mt * 16 + quad * 4] = w2;
            }
#pragma unroll
            for (int ks = 0; ks < 2; ks++) {
                bf16x8 pf = *(const bf16x8*)&Pw[wv][n * 72 + ks * 32 + quad * 8];
#pragma unroll
                for (int mt = 0; mt < 4; mt++)
                    o[i][mt] = __builtin_amdgcn_mfma_f32_16x16x32_bf16(vf[ks][mt], pf, o[i][mt], 0, 0, 0);
                lacc[i] = __builtin_amdgcn_mfma_f32_16x16x32_bf16(onesf.v, pf, lacc[i], 0, 0, 0);
            }
        }
        __syncthreads();   // publish next buffer (prefetch had full compute to land)
    }

#pragma unroll
    for (int i = 0; i < 4; i++) {
        int qg = q_lo[i] + n;
        float inv = 1.0f / lacc[i][0];
#pragma unroll
        for (int mt = 0; mt < 4; mt++) {
            f32x4 ov;
#pragma unroll
            for (int r2 = 0; r2 < 4; r2++) ov[r2] = o[i][mt][r2] * inv;
            *(f32x4*)(out + (size_t)(b * T + qg) * D + h * HD + mt * 16 + quad * 4) = ov;
        }
    }
}

// ---------------- launch ----------------
extern "C" void kernel_launch(void* const* d_in, const int* in_sizes, int n_in,
                              void* d_out, int out_size, void* d_ws, size_t ws_size,
                              hipStream_t stream) {
    const float* x   = (const float*)d_in[0];
    const float* cs  = (const float*)d_in[1];
    const float* sn  = (const float*)d_in[2];
    const float* wq  = (const float*)d_in[3];
    const float* wk  = (const float*)d_in[4];
    const float* wv  = (const float*)d_in[5];
    const float* wo  = (const float*)d_in[6];
    const float* gq  = (const float*)d_in[7];
    const float* gk  = (const float*)d_in[8];
    const float* gv  = (const float*)d_in[9];
    const float* go  = (const float*)d_in[10];
    float* out = (float*)d_out;

    uint8_t* w = (uint8_t*)d_ws;
    double* wsum  = (double*)w;
    float* xs     = (float*)(w + 256);
    size_t off = 256 + 4 * (size_t)R * 4;
    int8_t* Wq8 = (int8_t*)(w + off); off += (size_t)D * D;
    int8_t* Wk8 = (int8_t*)(w + off); off += (size_t)OKV * D;
    int8_t* Wv8 = (int8_t*)(w + off); off += (size_t)OKV * D;
    int8_t* Wo8 = (int8_t*)(w + off); off += (size_t)D * D;
    int8_t* Xq_q = (int8_t*)(w + off); off += (size_t)R * D;
    int8_t* Xq_k = (int8_t*)(w + off); off += (size_t)R * D;
    int8_t* Xq_v = (int8_t*)(w + off); off += (size_t)R * D;
    float* ab = (float*)(w + off); off += (size_t)R * D * 4;      // attention output (f32)
    float* vb = (float*)(w + off); off += (size_t)R * OKV * 4;    // v proj (f32)
    uint16_t* qhb = (uint16_t*)(w + off); off += (size_t)R * D * 2;
    // overlays (regions dead by the time they're written):
    uint16_t* khb = (uint16_t*)Xq_v;   // written by k-gemm AFTER v-gemm consumed Xq_v
    uint16_t* vtb = (uint16_t*)Xq_k;   // written by vtrans AFTER k-gemm consumed Xq_k
    int8_t*   Aq8 = Xq_q;              // written by rmsq AFTER q-gemm consumed Xq_q

    (void)hipMemsetAsync(wsum, 0, 64, stream);

    absmean4_kernel<<<dim3(256, 4), 256, 0, stream>>>(wq, wk, wv, wo, wsum);
    quantw4_kernel<<<dim3(1024, 4), 256, 0, stream>>>(wq, wk, wv, wo, Wq8, Wk8, Wv8, Wo8, wsum);

    rmsq3_kernel<<<R, 256, 0, stream>>>(x, gq, gk, gv, Xq_q, Xq_k, Xq_v,
                                        xs + 0 * R, xs + 1 * R, xs + 2 * R);

    // q (rope fused, bf16 out), then v (f32), then k (rope fused, bf16 over Xq_v)
    gemm_i8_mfma<128, 1><<<dim3(D / 128, R / 128), 256, 0, stream>>>(
        Xq_q, Wq8, qhb, xs + 0 * R, wsum, 0, D * D, D, cs, sn);
    gemm_i8_mfma<64, 0><<<dim3(OKV / 64, R / 128), 256, 0, stream>>>(
        Xq_v, Wv8, vb, xs + 2 * R, wsum, 2, OKV * D, OKV, cs, sn);
    gemm_i8_mfma<64, 1><<<dim3(OKV / 64, R / 128), 256, 0, stream>>>(
        Xq_k, Wk8, khb, xs + 1 * R, wsum, 1, OKV * D, OKV, cs, sn);

    vtrans_kernel<<<dim3(T / 64, B * KVH), 256, 0, stream>>>(vb, vtb);

    attn_mfma_kernel<<<dim3(8, H, B), 256, 0, stream>>>(qhb, khb, vtb, ab);

    rmsq_kernel<<<R, 256, 0, stream>>>(ab, go, Aq8, xs + 3 * R);
    gemm_i8_mfma<128, 0><<<dim3(D / 128, R / 128), 256, 0, stream>>>(
        Aq8, Wo8, out, xs + 3 * R, wsum, 3, D * D, D, cs, sn);
}